// Round 5
// baseline (75.006 us; speedup 1.0000x reference)
//
#include <hip/hip_runtime.h>
#include <stdint.h>

typedef unsigned short ushort_t;
typedef short short8 __attribute__((ext_vector_type(8)));
typedef float f32x4 __attribute__((ext_vector_type(4)));

#define CIN   64
#define COUT  128
#define BATCH 16
#define LPIX  1024               // 32*32
#define NTOT  (BATCH*LPIX)       // 16384
#define KTOT  5184               // 81 steps x 64
#define C2N   576                // CIN*9 features; c2 = f*64 + i (f-major)
#define PIXN  (BATCH*34*34)      // 18496 padded pixels
#define NSTEP 81                 // step s = c2s*9 + kk (slice-outer, tap-inner)
#define PART_ELEMS (NTOT*COUT)   // 2,097,152
#define FEAT_BLOCKS (PIXN/4)     // 4624
#define PREP_BLOCKS (COUT*KTOT/256) // 2592

// workspace layout (bytes)
#define FEAT_BYTES (PIXN*C2N*2)            // 21,307,392
#define W_OFF      FEAT_BYTES
#define W_BYTES    (COUT*KTOT*2)           // 1,327,104
#define PART_OFF   (W_OFF + W_BYTES)
#define PART_BYTES (PART_ELEMS*4)          // 8,388,608
#define WS_NEED    ((size_t)(PART_OFF + 3*PART_BYTES))

__device__ __forceinline__ ushort_t to_bf16(float f) {
  union { float f; uint32_t u; } v; v.f = f;
  uint32_t r = (v.u + 0x7fffu + ((v.u >> 16) & 1u)) >> 16;
  return (ushort_t)r;
}

// H_0..H_7 (physicists') of x, plus silu(x) at [8]
__device__ __forceinline__ void basis9(float x, float* o) {
  float hm = 1.f, h = 2.f * x;
  o[0] = hm; o[1] = h;
#pragma unroll
  for (int n = 1; n < 7; ++n) {
    float nx = 2.f * x * h - 2.f * (float)n * hm;
    hm = h; h = nx;
    o[n + 1] = nx;
  }
  o[8] = x / (1.f + __expf(-x));
}

__device__ __forceinline__ void load16(const void* g, void* l) {
  __builtin_amdgcn_global_load_lds(
      (const __attribute__((address_space(1))) uint32_t*)g,
      (__attribute__((address_space(3))) uint32_t*)l, 16, 0, 0);
}

// -------- fused prep: feat map (coalesced) + register-GEMM weight layout --
// feat[pix(b,34,34)][f*64+i] bf16.
// W2 ushort index = (((s*2+g)*128 + m)*4 + l4)*8 + e  where step s=c2s*9+kk,
// channel i=(g*4+l4)*8+e, basis f=c2s. A wave-load of fragment set (m-block,g)
// is then 1024B contiguous.
__global__ void prep_kernel(const float* __restrict__ x, ushort_t* __restrict__ feat,
                            const float* __restrict__ wb, const float* __restrict__ wsp,
                            const float* __restrict__ cc, ushort_t* __restrict__ W) {
  const int t = threadIdx.x;
  if (blockIdx.x < FEAT_BLOCKS) {
    const int lane = t & 63;                      // = cin index i
    const int pg = blockIdx.x * 4 + (t >> 6);     // padded pixel id
    const int xx = pg % 34;
    const int rest = pg / 34;
    const int yy = rest % 34;
    const int bb = rest / 34;
    float v = 0.f;
    if (xx >= 1 && xx <= 32 && yy >= 1 && yy <= 32)
      v = x[((bb * CIN + lane) * 32 + (yy - 1)) * 32 + (xx - 1)];
    float o[9];
    basis9(v, o);
    ushort_t* dst = feat + (size_t)pg * C2N + lane;
#pragma unroll
    for (int f = 0; f < 9; ++f) dst[f * 64] = to_bf16(o[f]);  // 128B/wave stores
  } else {
    const int idx = (blockIdx.x - FEAT_BLOCKS) * 256 + t;     // storage index
    const int e  = idx & 7;
    const int l4 = (idx >> 3) & 3;
    const int m  = (idx >> 5) & 127;
    const int g  = (idx >> 12) & 1;
    const int s  = idx >> 13;                                 // 0..80
    const int c2s = s / 9;
    const int kk  = s - c2s * 9;
    const int i   = (g * 4 + l4) * 8 + e;
    const int base = (i * COUT + m) * 9 + kk;
    const float val = (c2s < 8) ? wsp[base] * cc[base * 8 + c2s] : wb[base];
    W[idx] = to_bf16(val);
  }
}

// -------- GEMM: A in registers (coalesced prefetch), B halo in LDS --------
// out[n][m] = sum_s W[m][k(s)] * feat[pix(n,tap(s))][c2(s)]
// Barrier-free within a slice (9 steps); 2 barriers per slice change.
template <int KS>
__global__ __launch_bounds__(256, 2) void gemm_kernel(const ushort_t* __restrict__ feat,
                                                      const ushort_t* __restrict__ W,
                                                      float* __restrict__ out,
                                                      float* __restrict__ part) {
  __shared__ ushort_t Hb[1792 * 8];    // 28 KB halo: 224 px x 64 feats (204 used)
  const int t = threadIdx.x;
  const int lane = t & 63;
  const int wave = t >> 6;
  const int wm = wave >> 1, wn = wave & 1;

  // XCD-chunked remap, nb-major: consecutive logicals share the N-tile.
  const int logical = (blockIdx.x & 7) * (gridDim.x >> 3) + (blockIdx.x >> 3);
  const int nb = logical / KS;
  const int slice = logical - nb * KS;
  const int lo = (slice * NSTEP) / KS;
  const int hi = ((slice + 1) * NSTEP) / KS;

  const int b  = nb >> 3;               // image
  const int y0 = (nb & 7) * 4;          // padded rows y0..y0+5
  const int pixbase = (b * 34 + y0) * 34;

  const char* Fb = (const char*)feat;
  // per-lane A base: + s*16384 + g*8192 + mf*1024 later
  const char* Ab = (const char*)W + wm * 4096 +
                   (lane & 15) * 64 + (lane >> 4) * 16;

  f32x4 acc[4][4];
#pragma unroll
  for (int a = 0; a < 4; ++a)
#pragma unroll
    for (int c = 0; c < 4; ++c) acc[a][c] = (f32x4)0.f;

  auto stage_halo = [&](int c2s) {      // 7 DMA loads/thread
    const char* base = Fb + (size_t)pixbase * (C2N * 2) + c2s * 128;
#pragma unroll
    for (int it = 0; it < 7; ++it) {
      const int q = it * 256 + t;           // 1792 chunks: 224 px x 8
      const int hp = q >> 3, sl = q & 7;
      load16(base + hp * (C2N * 2) + ((sl ^ (hp & 7)) << 4), &Hb[q * 8]);
    }
  };

#define PREFETCH_A(A, s)                                                     \
  {                                                                          \
    const char* p_ = Ab + (size_t)(s) * 16384;                               \
    _Pragma("unroll") for (int mf_ = 0; mf_ < 4; ++mf_)                      \
        _Pragma("unroll") for (int g_ = 0; g_ < 2; ++g_)                     \
        (A)[mf_ * 2 + g_] =                                                  \
            *(const short8*)(p_ + g_ * 8192 + mf_ * 1024);                   \
  }

#define COMPUTE_S(A, s)                                                      \
  {                                                                          \
    const int kk_ = (s) % 9;                                                 \
    const int dy_ = kk_ / 3, dx_ = kk_ - dy_ * 3;                            \
    _Pragma("unroll") for (int ks_ = 0; ks_ < 2; ++ks_) {                    \
      short8 bv_[4];                                                         \
      const int kslot_ = ks_ * 4 + (lane >> 4);                              \
      _Pragma("unroll") for (int nf_ = 0; nf_ < 4; ++nf_) {                  \
        const int nl_ = wn * 64 + nf_ * 16 + (lane & 15);                    \
        const int L_ = ((nl_ >> 5) + dy_) * 34 + (nl_ & 31) + dx_;           \
        bv_[nf_] = *(const short8*)&Hb[L_ * 64 + ((kslot_ ^ (L_ & 7)) << 3)];\
      }                                                                      \
      _Pragma("unroll") for (int mf_ = 0; mf_ < 4; ++mf_)                    \
          _Pragma("unroll") for (int nf_ = 0; nf_ < 4; ++nf_)                \
          acc[mf_][nf_] = __builtin_amdgcn_mfma_f32_16x16x32_bf16(           \
              (A)[mf_ * 2 + ks_], bv_[nf_], acc[mf_][nf_], 0, 0, 0);         \
    }                                                                        \
  }

  short8 a0[8], a1[8];
  int c2s_cur = lo / 9;
  stage_halo(c2s_cur);
  PREFETCH_A(a0, lo);
  __syncthreads();

  bool use0 = true;
  for (int s = lo; s < hi; ++s) {
    const int cs = s / 9;
    if (cs != c2s_cur) {                 // slice change: restage halo
      __syncthreads();                   // all waves done reading old halo
      stage_halo(cs);
      __syncthreads();                   // DMA complete
      c2s_cur = cs;
    }
    if (use0) {
      if (s + 1 < hi) PREFETCH_A(a1, s + 1);
      COMPUTE_S(a0, s);
    } else {
      if (s + 1 < hi) PREFETCH_A(a0, s + 1);
      COMPUTE_S(a1, s);
    }
    use0 = !use0;
  }

  float* dst = slice ? (part + (size_t)(slice - 1) * PART_ELEMS) : out;
#pragma unroll
  for (int mf = 0; mf < 4; ++mf)
#pragma unroll
    for (int nf = 0; nf < 4; ++nf)
#pragma unroll
      for (int rg = 0; rg < 4; ++rg) {
        const int m = wm * 64 + mf * 16 + (lane >> 4) * 4 + rg;
        const int n = nb * 128 + wn * 64 + nf * 16 + (lane & 15);
        const int bb = n >> 10, ll = n & 1023;
        dst[(bb * COUT + m) * LPIX + ll] = acc[mf][nf][rg];
      }
}

template <int NP>
__global__ void add_kernel(float* __restrict__ out, const float* __restrict__ part) {
  const int i = (blockIdx.x * 256 + threadIdx.x) * 4;
  f32x4 a = *(const f32x4*)&out[i];
#pragma unroll
  for (int j = 0; j < NP; ++j)
    a += *(const f32x4*)&part[(size_t)j * PART_ELEMS + i];
  *(f32x4*)&out[i] = a;
}

// ---------------- fallback (only if ws too small): direct evaluation -----
__global__ void naive_kernel(const float* __restrict__ x, const float* __restrict__ wb,
                             const float* __restrict__ wsp, const float* __restrict__ cc,
                             float* __restrict__ out) {
  const int idx = blockIdx.x * 256 + threadIdx.x;
  if (idx >= BATCH * COUT * LPIX) return;
  const int l = idx & 1023, o = (idx >> 10) & 127, b = idx >> 17;
  const int h = l >> 5, w = l & 31;
  float acc = 0.f;
  for (int i = 0; i < CIN; ++i)
    for (int kk = 0; kk < 9; ++kk) {
      const int yy = h + kk / 3 - 1, xx = w + kk % 3 - 1;
      const float v = (yy >= 0 && yy < 32 && xx >= 0 && xx < 32)
                          ? x[((b * CIN + i) * 32 + yy) * 32 + xx] : 0.f;
      float ftr[9];
      basis9(v, ftr);
      const int base = (i * COUT + o) * 9 + kk;
      const float* cp = cc + base * 8;
      float dot = 0.f;
#pragma unroll
      for (int f = 0; f < 8; ++f) dot += cp[f] * ftr[f];
      acc += wsp[base] * dot + wb[base] * ftr[8];
    }
  out[idx] = acc;
}

extern "C" void kernel_launch(void* const* d_in, const int* in_sizes, int n_in,
                              void* d_out, int out_size, void* d_ws, size_t ws_size,
                              hipStream_t stream) {
  const float* x  = (const float*)d_in[0];
  const float* wb = (const float*)d_in[1];
  const float* wsp = (const float*)d_in[2];
  const float* cc = (const float*)d_in[3];
  float* out = (float*)d_out;

  if (ws_size < WS_NEED) {
    naive_kernel<<<(BATCH * COUT * LPIX + 255) / 256, 256, 0, stream>>>(x, wb, wsp, cc, out);
    return;
  }

  char* ws = (char*)d_ws;
  ushort_t* feat = (ushort_t*)ws;
  ushort_t* W    = (ushort_t*)(ws + W_OFF);
  float* part    = (float*)(ws + PART_OFF);

  prep_kernel<<<FEAT_BLOCKS + PREP_BLOCKS, 256, 0, stream>>>(x, feat, wb, wsp, cc, W);
  gemm_kernel<4><<<128 * 4, 256, 0, stream>>>(feat, W, out, part);
  add_kernel<3><<<PART_ELEMS / 1024, 256, 0, stream>>>(out, part);
}

// Round 6
// 50.107 us; speedup vs baseline: 1.4969x; 1.4969x over previous
//
#include <hip/hip_runtime.h>
#include <stdint.h>

typedef unsigned short ushort_t;
typedef short short8 __attribute__((ext_vector_type(8)));
typedef float f32x4 __attribute__((ext_vector_type(4)));

#define CIN   64
#define COUT  128
#define BATCH 16
#define LPIX  1024               // 32*32
#define NTOT  (BATCH*LPIX)       // 16384
#define KTOT  5184               // 81 x 64
#define C2N   576                // CIN*9 features; c2 = f*64 + i (f-major)
#define PIXN  (BATCH*34*34)      // 18496 padded pixels
#define WROW  KTOT               // ushorts per Cout row
#define NSTEP 81                 // step s: c2-slice s/9 (=basis f), tap s%9
#define PART_ELEMS (NTOT*COUT)   // 2,097,152
#define FEAT_BLOCKS (PIXN/4)     // 4624
#define PREP_BLOCKS (COUT*KTOT/256) // 2592

// workspace layout (bytes)
#define FEAT_BYTES (PIXN*C2N*2)            // 21,307,392
#define W_OFF      FEAT_BYTES
#define W_BYTES    (COUT*KTOT*2)           // 1,327,104
#define PART_OFF   (W_OFF + W_BYTES)
#define PART_BYTES (PART_ELEMS*4)          // 8,388,608
#define WS_NEED(KS) ((size_t)(PART_OFF + (size_t)((KS)-1)*PART_BYTES))

__device__ __forceinline__ ushort_t to_bf16(float f) {
  union { float f; uint32_t u; } v; v.f = f;
  uint32_t r = (v.u + 0x7fffu + ((v.u >> 16) & 1u)) >> 16;
  return (ushort_t)r;
}

// H_0..H_7 (physicists') of x, plus silu(x) at [8]
__device__ __forceinline__ void basis9(float x, float* o) {
  float hm = 1.f, h = 2.f * x;
  o[0] = hm; o[1] = h;
#pragma unroll
  for (int n = 1; n < 7; ++n) {
    float nx = 2.f * x * h - 2.f * (float)n * hm;
    hm = h; h = nx;
    o[n + 1] = nx;
  }
  o[8] = x / (1.f + __expf(-x));
}

__device__ __forceinline__ void load16(const void* g, void* l) {
  __builtin_amdgcn_global_load_lds(
      (const __attribute__((address_space(1))) uint32_t*)g,
      (__attribute__((address_space(3))) uint32_t*)l, 16, 0, 0);
}

// -------- fused prep (R4-verified): coalesced feat + swizzled W -----------
// feat[pix(b,34,34)][f*64+i] bf16 (128B/wave stores).
// W[m][k], k=kk*576+f*64+i; 16B chunk (k>>3) xored with m&7 within each
// 64-k group; written in storage order (coalesced 2B stores).
__global__ void prep_kernel(const float* __restrict__ x, ushort_t* __restrict__ feat,
                            const float* __restrict__ wb, const float* __restrict__ wsp,
                            const float* __restrict__ cc, ushort_t* __restrict__ W) {
  const int t = threadIdx.x;
  if (blockIdx.x < FEAT_BLOCKS) {
    const int lane = t & 63;                      // = cin index i
    const int pg = blockIdx.x * 4 + (t >> 6);     // padded pixel id
    const int xx = pg % 34;
    const int rest = pg / 34;
    const int yy = rest % 34;
    const int bb = rest / 34;
    float v = 0.f;
    if (xx >= 1 && xx <= 32 && yy >= 1 && yy <= 32)
      v = x[((bb * CIN + lane) * 32 + (yy - 1)) * 32 + (xx - 1)];
    float o[9];
    basis9(v, o);
    ushort_t* dst = feat + (size_t)pg * C2N + lane;
#pragma unroll
    for (int f = 0; f < 9; ++f) dst[f * 64] = to_bf16(o[f]);
  } else {
    const int idx = (blockIdx.x - FEAT_BLOCKS) * 256 + t;     // storage index
    const int m = idx / WROW;
    const int pos = idx - m * WROW;
    const int k = (pos & ~63) | ((((pos >> 3) & 7) ^ (m & 7)) << 3) | (pos & 7);
    const int kk = k / C2N;
    const int r = k - kk * C2N;
    const int f = r >> 6;
    const int i = r & 63;
    const int base = (i * COUT + m) * 9 + kk;
    const float val = (f < 8) ? wsp[base] * cc[base * 8 + f] : wb[base];
    W[idx] = to_bf16(val);
  }
}

// -------- GEMM (R2-verified structure): A dbuf LDS, 6-row halo ------------
// out[n][m] = sum_s W[m][k(s)] * feat[pix(n,tap(s))][c2(s)]
// step s: slice c2s=s/9 (basis), tap kk=s%9. Halo staged once per slice.
template <int KS>
__global__ __launch_bounds__(256, 2) void gemm_kernel(const ushort_t* __restrict__ feat,
                                                      const ushort_t* __restrict__ W,
                                                      float* __restrict__ out,
                                                      float* __restrict__ part) {
  __shared__ ushort_t Ab[2][8192];     // [m=128][k=64], slot-swizzled, dbuf
  __shared__ ushort_t Hb[1792 * 8];    // halo: 224 px x 64 feats (204 used)
  const int t = threadIdx.x;
  const int lane = t & 63;
  const int wave = t >> 6;
  const int wm = wave >> 1, wn = wave & 1;

  // XCD-chunked remap, nb-major: consecutive logicals share the N-tile.
  const int logical = (blockIdx.x & 7) * (gridDim.x >> 3) + (blockIdx.x >> 3);
  const int nb = logical / KS;
  const int slice = logical - nb * KS;
  const int lo = (slice * NSTEP) / KS;
  const int hi = ((slice + 1) * NSTEP) / KS;

  const int b  = nb >> 3;               // image
  const int y0 = (nb & 7) * 4;          // padded rows y0..y0+5
  const int pixbase = (b * 34 + y0) * 34;

  const char* Wb = (const char*)W;
  const char* Fb = (const char*)feat;

  f32x4 acc[4][4];
#pragma unroll
  for (int a = 0; a < 4; ++a)
#pragma unroll
    for (int c = 0; c < 4; ++c) acc[a][c] = (f32x4)0.f;

  auto stage_halo = [&](int c2s) {      // 7 DMA loads/thread
    const char* base = Fb + (size_t)pixbase * (C2N * 2) + c2s * 128;
#pragma unroll
    for (int it = 0; it < 7; ++it) {
      const int q = it * 256 + t;           // 1792 chunks: 224 px x 8
      const int hp = q >> 3, sl = q & 7;
      load16(base + hp * (C2N * 2) + ((sl ^ (hp & 7)) << 4), &Hb[q * 8]);
    }
  };

  auto stageA = [&](int p, int c2s, int kk) {   // 4 DMA loads/thread
    const int c64 = kk * 9 + c2s;               // 64-wide K-chunk in W rows
#pragma unroll
    for (int q = 0; q < 4; ++q) {
      const int idx16 = q * 256 + t;
      const int m = idx16 >> 3, ccn = idx16 & 7;
      load16(Wb + m * (WROW * 2) + c64 * 128 + ccn * 16, &Ab[p][idx16 * 8]);
    }
  };

  auto compute = [&](int p, int dy, int dx) {
#pragma unroll
    for (int ks = 0; ks < 2; ++ks) {
      short8 av[4], bv[4];
      const int kslot = ks * 4 + (lane >> 4);
#pragma unroll
      for (int mf = 0; mf < 4; ++mf) {
        const int row = wm * 64 + mf * 16 + (lane & 15);
        av[mf] = *(const short8*)&Ab[p][row * 64 + ((kslot ^ (row & 7)) << 3)];
      }
#pragma unroll
      for (int nf = 0; nf < 4; ++nf) {
        const int nl = wn * 64 + nf * 16 + (lane & 15);
        const int L = ((nl >> 5) + dy) * 34 + (nl & 31) + dx;
        bv[nf] = *(const short8*)&Hb[L * 64 + ((kslot ^ (L & 7)) << 3)];
      }
#pragma unroll
      for (int mf = 0; mf < 4; ++mf)
#pragma unroll
        for (int nf = 0; nf < 4; ++nf)
          acc[mf][nf] = __builtin_amdgcn_mfma_f32_16x16x32_bf16(av[mf], bv[nf],
                                                                acc[mf][nf], 0, 0, 0);
    }
  };

  int c2s = lo / 9;
  int kk  = lo - c2s * 9;
  stage_halo(c2s);
  stageA(0, c2s, kk);
  __syncthreads();
  int p = 0;
  for (int s = lo; s < hi; ++s) {
    int nkk = kk + 1, nc2s = c2s;
    bool newhalo = false;
    if (nkk == 9) { nkk = 0; ++nc2s; newhalo = true; }
    if (s + 1 < hi) stageA(p ^ 1, nc2s, nkk);
    const int dy = kk / 3, dx = kk - dy * 3;
    compute(p, dy, dx);
    __syncthreads();
    if (s + 1 < hi && newhalo) {
      stage_halo(nc2s);
      __syncthreads();
    }
    kk = nkk; c2s = nc2s; p ^= 1;
  }

  float* dst = slice ? (part + (size_t)(slice - 1) * PART_ELEMS) : out;
#pragma unroll
  for (int mf = 0; mf < 4; ++mf)
#pragma unroll
    for (int nf = 0; nf < 4; ++nf)
#pragma unroll
      for (int rg = 0; rg < 4; ++rg) {
        const int m = wm * 64 + mf * 16 + (lane >> 4) * 4 + rg;
        const int n = nb * 128 + wn * 64 + nf * 16 + (lane & 15);
        const int bb = n >> 10, ll = n & 1023;
        dst[(bb * COUT + m) * LPIX + ll] = acc[mf][nf][rg];
      }
}

template <int NP>
__global__ void add_kernel(float* __restrict__ out, const float* __restrict__ part) {
  const int i = (blockIdx.x * 256 + threadIdx.x) * 4;
  f32x4 a = *(const f32x4*)&out[i];
#pragma unroll
  for (int j = 0; j < NP; ++j)
    a += *(const f32x4*)&part[(size_t)j * PART_ELEMS + i];
  *(f32x4*)&out[i] = a;
}

// ---------------- fallback (only if ws too small): direct evaluation -----
__global__ void naive_kernel(const float* __restrict__ x, const float* __restrict__ wb,
                             const float* __restrict__ wsp, const float* __restrict__ cc,
                             float* __restrict__ out) {
  const int idx = blockIdx.x * 256 + threadIdx.x;
  if (idx >= BATCH * COUT * LPIX) return;
  const int l = idx & 1023, o = (idx >> 10) & 127, b = idx >> 17;
  const int h = l >> 5, w = l & 31;
  float acc = 0.f;
  for (int i = 0; i < CIN; ++i)
    for (int kk = 0; kk < 9; ++kk) {
      const int yy = h + kk / 3 - 1, xx = w + kk % 3 - 1;
      const float v = (yy >= 0 && yy < 32 && xx >= 0 && xx < 32)
                          ? x[((b * CIN + i) * 32 + yy) * 32 + xx] : 0.f;
      float ftr[9];
      basis9(v, ftr);
      const int base = (i * COUT + o) * 9 + kk;
      const float* cp = cc + base * 8;
      float dot = 0.f;
#pragma unroll
      for (int f = 0; f < 8; ++f) dot += cp[f] * ftr[f];
      acc += wsp[base] * dot + wb[base] * ftr[8];
    }
  out[idx] = acc;
}

extern "C" void kernel_launch(void* const* d_in, const int* in_sizes, int n_in,
                              void* d_out, int out_size, void* d_ws, size_t ws_size,
                              hipStream_t stream) {
  const float* x  = (const float*)d_in[0];
  const float* wb = (const float*)d_in[1];
  const float* wsp = (const float*)d_in[2];
  const float* cc = (const float*)d_in[3];
  float* out = (float*)d_out;

  if (ws_size < WS_NEED(2)) {
    naive_kernel<<<(BATCH * COUT * LPIX + 255) / 256, 256, 0, stream>>>(x, wb, wsp, cc, out);
    return;
  }

  char* ws = (char*)d_ws;
  ushort_t* feat = (ushort_t*)ws;
  ushort_t* W    = (ushort_t*)(ws + W_OFF);
  float* part    = (float*)(ws + PART_OFF);

  prep_kernel<<<FEAT_BLOCKS + PREP_BLOCKS, 256, 0, stream>>>(x, feat, wb, wsp, cc, W);
  if (ws_size >= WS_NEED(4)) {
    gemm_kernel<4><<<128 * 4, 256, 0, stream>>>(feat, W, out, part);
    add_kernel<3><<<PART_ELEMS / 1024, 256, 0, stream>>>(out, part);
  } else {
    gemm_kernel<2><<<128 * 2, 256, 0, stream>>>(feat, W, out, part);
    add_kernel<1><<<PART_ELEMS / 1024, 256, 0, stream>>>(out, part);
  }
}